// Round 12
// baseline (751.379 us; speedup 1.0000x reference)
//
#include <hip/hip_runtime.h>

#define NROWS 32768
#define KC 8192
#define DDIM 256
#define D4 64
#define CAP 128
#define DACC 2.0f          // acc-domain margin = 2/4096 = 4.88e-4 in score units
#define MT 128
#define SEGC 1024
#define PAN 64
#define NPAN 16
#define PRESEG 2           // prepass samples 2 segments = 2048 codes

typedef _Float16 half8 __attribute__((ext_vector_type(8)));
typedef float f32x4 __attribute__((ext_vector_type(4)));
typedef unsigned int uint;

union H4 { ushort4 u; _Float16 h[4]; };

// fmax-reduce over each 16-lane group via DPP row_ror (pure VALU)
template <int CTRL>
__device__ __forceinline__ float rormax_step(float x) {
  const int v = __builtin_amdgcn_mov_dpp(__float_as_int(x), CTRL, 0xf, 0xf, true);
  return fmaxf(x, __int_as_float(v));
}
__device__ __forceinline__ float redmax16(float x) {
  x = rormax_step<0x121>(x);
  x = rormax_step<0x122>(x);
  x = rormax_step<0x124>(x);
  x = rormax_step<0x128>(x);
  return x;
}

// ---------------- kernel 1: bit-exact numpy pairwise row norm ----------------
__global__ __launch_bounds__(256) void vq_znorm(const float* __restrict__ z,
                                                float* __restrict__ An) {
#pragma clang fp contract(off)
  const int row = blockIdx.x * 256 + threadIdx.x;
  const float4* p4 = (const float4*)(z + (size_t)row * 256);
  float halves[2];
#pragma unroll
  for (int h = 0; h < 2; ++h) {
    float r[8];
    float4 a = p4[h * 32 + 0], b = p4[h * 32 + 1];
    r[0] = a.x * a.x; r[1] = a.y * a.y; r[2] = a.z * a.z; r[3] = a.w * a.w;
    r[4] = b.x * b.x; r[5] = b.y * b.y; r[6] = b.z * b.z; r[7] = b.w * b.w;
    for (int i = 1; i < 16; ++i) {  // 8-elem chunks in numpy pairwise order
      a = p4[h * 32 + i * 2];
      b = p4[h * 32 + i * 2 + 1];
      r[0] += a.x * a.x; r[1] += a.y * a.y; r[2] += a.z * a.z; r[3] += a.w * a.w;
      r[4] += b.x * b.x; r[5] += b.y * b.y; r[6] += b.z * b.z; r[7] += b.w * b.w;
    }
    halves[h] = ((r[0] + r[1]) + (r[2] + r[3])) + ((r[4] + r[5]) + (r[6] + r[7]));
  }
  An[row] = halves[0] + halves[1];
}

// ---------------- kernel 2: f32 -> f16 conversion (+ scale e by 2^13) + init ----------------
__global__ __launch_bounds__(256) void vq_convert(const float* __restrict__ z,
                                                  const float* __restrict__ emb,
                                                  _Float16* __restrict__ z16,
                                                  _Float16* __restrict__ e16,
                                                  int* __restrict__ cnt) {
  const int tid = blockIdx.x * 256 + threadIdx.x;  // 524288 threads
  const float4* z4 = (const float4*)z;
  const float4* e4 = (const float4*)emb;
  ushort4* z16u = (ushort4*)z16;
  ushort4* e16u = (ushort4*)e16;
#pragma unroll
  for (int t = 0; t < 4; ++t) {
    const int i = tid + t * 524288;
    const float4 v = z4[i];
    H4 o;
    o.h[0] = (_Float16)v.x; o.h[1] = (_Float16)v.y;
    o.h[2] = (_Float16)v.z; o.h[3] = (_Float16)v.w;
    z16u[i] = o.u;
  }
  {
    const int i = tid;  // 524288 = 8192*64
    const float4 v = e4[i];
    H4 o;
    o.h[0] = (_Float16)(v.x * 8192.0f); o.h[1] = (_Float16)(v.y * 8192.0f);
    o.h[2] = (_Float16)(v.z * 8192.0f); o.h[3] = (_Float16)(v.w * 8192.0f);
    e16u[i] = o.u;
  }
  if (tid < NROWS) cnt[tid] = 0;
}

// ---------------- kernel 3: pre-pass — codes 0..2047, rowthr = max acc ----------------
// Same pipelined streaming path as the main kernel (k-ascending MFMA chain).
__global__ __launch_bounds__(256) void vq_prepass(
    const _Float16* __restrict__ z16, const _Float16* __restrict__ e16,
    float* __restrict__ rowthr) {
  const int brow = blockIdx.x * MT;  // grid 256
  const int tid = threadIdx.x;
  const int lane = tid & 63, w = tid >> 6;
  const int l15 = lane & 15, l4 = lane >> 4;
  const int wr = w >> 1, wc = w & 1;
  const int wrow = wr * 64;

  half8 af[4][8];
#pragma unroll
  for (int m = 0; m < 4; ++m)
#pragma unroll
    for (int k = 0; k < 8; ++k)
      af[m][k] = *(const half8*)(z16 + (size_t)(brow + wrow + m * 16 + l15) * DDIM + k * 32 + l4 * 8);

  float tm[4][4];
#pragma unroll
  for (int m = 0; m < 4; ++m)
#pragma unroll
    for (int r = 0; r < 4; ++r) tm[m][r] = -3.4e38f;

  const _Float16* eb0 = e16 + (size_t)(wc * 32 + l15) * DDIM + l4 * 8;
  const _Float16* eb1 = eb0 + 16 * DDIM;

  // full-panel register double-buffer: preload panel 0
  half8 bb0[8], bb1[8];
#pragma unroll
  for (int k = 0; k < 8; ++k) {
    bb0[k] = *(const half8*)(eb0 + k * 32);
    bb1[k] = *(const half8*)(eb1 + k * 32);
  }

  const int NP = PRESEG * NPAN;
  for (int p = 0; p < NP; ++p) {
    const int pp = (p + 1 < NP) ? p + 1 : p;  // prefetch target (self at last)
    const _Float16* nb0 = eb0 + (size_t)pp * PAN * DDIM;
    const _Float16* nb1 = eb1 + (size_t)pp * PAN * DDIM;
    f32x4 acc[4][2] = {{{0.f}}};
#pragma unroll
    for (int k = 0; k < 8; ++k) {
      const half8 u0 = bb0[k], u1 = bb1[k];
#pragma unroll
      for (int m = 0; m < 4; ++m)
        acc[m][0] = __builtin_amdgcn_mfma_f32_16x16x32_f16(af[m][k], u0, acc[m][0], 0, 0, 0);
#pragma unroll
      for (int m = 0; m < 4; ++m)
        acc[m][1] = __builtin_amdgcn_mfma_f32_16x16x32_f16(af[m][k], u1, acc[m][1], 0, 0, 0);
      // rotate: same k-slice of next panel (≈7 k-steps of MFMA cover before use)
      bb0[k] = *(const half8*)(nb0 + k * 32);
      bb1[k] = *(const half8*)(nb1 + k * 32);
    }
#pragma unroll
    for (int m = 0; m < 4; ++m)
#pragma unroll
      for (int r = 0; r < 4; ++r)
        tm[m][r] = fmaxf(tm[m][r], fmaxf(acc[m][0][r], acc[m][1][r]));
  }

  __shared__ float red[2][128];  // [wc][row-in-tile]
#pragma unroll
  for (int m = 0; m < 4; ++m)
#pragma unroll
    for (int r = 0; r < 4; ++r) {
      const float mx = redmax16(tm[m][r]);
      if (l15 == 0) red[wc][wrow + m * 16 + l4 * 4 + r] = mx;
    }
  __syncthreads();
  if (tid < 128) rowthr[brow + tid] = fmaxf(red[0][tid], red[1][tid]);
}

// ---------------- kernel 4: barrier-free pipelined GEMM + constant-threshold filter ----
// grid 2048 = 256 M-tiles x 8 segments; seg = bid&7 (== XCD id -> e-segment L2-hot).
// No LDS/barriers. af[4][8] register(AGPR)-resident; B full-panel register dbuf with
// per-k rotation -> every load has a full panel of MFMA latency cover.
__global__ __launch_bounds__(256) void vq_gemm_filter(
    const _Float16* __restrict__ z16, const _Float16* __restrict__ e16,
    const float* __restrict__ rowthr, int* __restrict__ cnt,
    uint* __restrict__ list) {
  const int bid = blockIdx.x;
  const int seg = bid & 7, mIdx = bid >> 3;
  const int brow = mIdx * MT;
  const int c0seg = seg * SEGC;
  const int tid = threadIdx.x;
  const int lane = tid & 63, w = tid >> 6;
  const int l15 = lane & 15, l4 = lane >> 4;
  const int wr = w >> 1, wc = w & 1;
  const int wrow = wr * 64;

  half8 af[4][8];
#pragma unroll
  for (int m = 0; m < 4; ++m)
#pragma unroll
    for (int k = 0; k < 8; ++k)
      af[m][k] = *(const half8*)(z16 + (size_t)(brow + wrow + m * 16 + l15) * DDIM + k * 32 + l4 * 8);

  float Lthr[4][4];
#pragma unroll
  for (int m = 0; m < 4; ++m)
#pragma unroll
    for (int r = 0; r < 4; ++r)
      Lthr[m][r] = rowthr[brow + wrow + m * 16 + l4 * 4 + r] - DACC;

  const _Float16* eb0 = e16 + (size_t)(c0seg + wc * 32 + l15) * DDIM + l4 * 8;
  const _Float16* eb1 = eb0 + 16 * DDIM;

  half8 bb0[8], bb1[8];
#pragma unroll
  for (int k = 0; k < 8; ++k) {
    bb0[k] = *(const half8*)(eb0 + k * 32);
    bb1[k] = *(const half8*)(eb1 + k * 32);
  }

  for (int p = 0; p < NPAN; ++p) {
    const int pp = (p + 1 < NPAN) ? p + 1 : p;
    const _Float16* nb0 = eb0 + (size_t)pp * PAN * DDIM;
    const _Float16* nb1 = eb1 + (size_t)pp * PAN * DDIM;
    f32x4 acc[4][2] = {{{0.f}}};
#pragma unroll
    for (int k = 0; k < 8; ++k) {
      const half8 u0 = bb0[k], u1 = bb1[k];
#pragma unroll
      for (int m = 0; m < 4; ++m)
        acc[m][0] = __builtin_amdgcn_mfma_f32_16x16x32_f16(af[m][k], u0, acc[m][0], 0, 0, 0);
#pragma unroll
      for (int m = 0; m < 4; ++m)
        acc[m][1] = __builtin_amdgcn_mfma_f32_16x16x32_f16(af[m][k], u1, acc[m][1], 0, 0, 0);
      bb0[k] = *(const half8*)(nb0 + k * 32);
      bb1[k] = *(const half8*)(nb1 + k * 32);
    }
    // epilogue: 32 compares, rare appends
#pragma unroll
    for (int m = 0; m < 4; ++m)
#pragma unroll
      for (int n = 0; n < 2; ++n)
#pragma unroll
        for (int r = 0; r < 4; ++r) {
          if (acc[m][n][r] >= Lthr[m][r]) {
            const int row = brow + wrow + m * 16 + l4 * 4 + r;
            const int code = c0seg + p * PAN + wc * 32 + n * 16 + l15;
            const int pos = atomicAdd(cnt + row, 1);
            if (pos < CAP) list[(size_t)row * CAP + pos] = (uint)code;
          }
        }
  }
}

// ---------------- kernel 5: exact recheck (bit-exact np chain) + gather ----------------
__global__ __launch_bounds__(256) void vq_recheck_gather(
    const float* __restrict__ z, const float* __restrict__ emb,
    const float* __restrict__ An, const int* __restrict__ cnt,
    const uint* __restrict__ list, float* __restrict__ out) {
  __shared__ float4 zsh[4][64];
  const int wv = threadIdx.x >> 6;
  const int lane = threadIdx.x & 63;
  const int row = blockIdx.x * 4 + wv;
  const float4* e4 = (const float4*)emb;

  zsh[wv][lane] = ((const float4*)z)[(size_t)row * D4 + lane];
  __syncthreads();

  const int nc = cnt[row];
  const float Ar = An[row];
  float bs = 3.4e38f;
  int bi = 0x7fffffff;

  if (nc <= CAP) {
    for (int c = lane; c < nc; c += 64) {
      const int code = (int)list[(size_t)row * CAP + c];
      const float4* ep = e4 + (size_t)code * D4;
      float p = 0.f;
#pragma unroll
      for (int ch = 0; ch < 8; ++ch) {
        float4 ev[8];
#pragma unroll
        for (int j = 0; j < 8; ++j) ev[j] = ep[ch * 8 + j];  // batched loads
#pragma unroll
        for (int j = 0; j < 8; ++j) {  // exact ascending-d fma chain
          const float4 zv = zsh[wv][ch * 8 + j];
          p = fmaf(zv.x, ev[j].x, p); p = fmaf(zv.y, ev[j].y, p);
          p = fmaf(zv.z, ev[j].z, p); p = fmaf(zv.w, ev[j].w, p);
        }
      }
      const float s = Ar - 2.0f * p;  // fl(A-2p), 2p exact
      if (s < bs || (s == bs && code < bi)) { bs = s; bi = code; }
    }
  } else {  // overflow fallback (P ~ 1e-8/row with 2048-code prepass): exact full scan
    for (int code = lane; code < KC; code += 64) {
      const float4* ep = e4 + (size_t)code * D4;
      float p = 0.f;
#pragma unroll 2
      for (int ch = 0; ch < 8; ++ch) {
        float4 ev[8];
#pragma unroll
        for (int j = 0; j < 8; ++j) ev[j] = ep[ch * 8 + j];
#pragma unroll
        for (int j = 0; j < 8; ++j) {
          const float4 zv = zsh[wv][ch * 8 + j];
          p = fmaf(zv.x, ev[j].x, p); p = fmaf(zv.y, ev[j].y, p);
          p = fmaf(zv.z, ev[j].z, p); p = fmaf(zv.w, ev[j].w, p);
        }
      }
      const float s = Ar - 2.0f * p;
      if (s < bs || (s == bs && code < bi)) { bs = s; bi = code; }
    }
  }
#pragma unroll
  for (int off = 1; off < 64; off <<= 1) {
    const float os = __shfl_xor(bs, off, 64);
    const int oi = __shfl_xor(bi, off, 64);
    if (os < bs || (os == bs && oi < bi)) { bs = os; bi = oi; }
  }
  const float4 v = e4[(size_t)bi * D4 + lane];
  ((float4*)out)[(size_t)row * D4 + lane] = v;
}

extern "C" void kernel_launch(void* const* d_in, const int* in_sizes, int n_in,
                              void* d_out, int out_size, void* d_ws, size_t ws_size,
                              hipStream_t stream) {
  const float* z = (const float*)d_in[0];    // [32768, 256] f32
  const float* emb = (const float*)d_in[1];  // [8192, 256] f32
  float* out = (float*)d_out;                // [32768, 256] f32

  char* wsb = (char*)d_ws;
  float* An = (float*)(wsb);                         // 128 KB
  int* cnt = (int*)(wsb + (128 << 10));              // 128 KB
  float* rowthr = (float*)(wsb + (256 << 10));       // 128 KB
  uint* list = (uint*)(wsb + (512 << 10));           // 32768*128*4B = 16 MB
  _Float16* z16 = (_Float16*)(wsb + (512 << 10) + (16 << 20));  // 16 MB
  _Float16* e16 = (_Float16*)(wsb + (512 << 10) + (32 << 20));  // 4 MB

  vq_znorm<<<NROWS / 256, 256, 0, stream>>>(z, An);
  vq_convert<<<2048, 256, 0, stream>>>(z, emb, z16, e16, cnt);
  vq_prepass<<<NROWS / MT, 256, 0, stream>>>(z16, e16, rowthr);
  vq_gemm_filter<<<2048, 256, 0, stream>>>(z16, e16, rowthr, cnt, list);
  vq_recheck_gather<<<NROWS / 4, 256, 0, stream>>>(z, emb, An, cnt, list, out);
}